// Round 3
// baseline (3243.934 us; speedup 1.0000x reference)
//
#include <hip/hip_runtime.h>

typedef __bf16 bf16;
typedef __bf16 bf16x8 __attribute__((ext_vector_type(8)));
typedef __bf16 bf16x4 __attribute__((ext_vector_type(4)));
typedef float  f32x4  __attribute__((ext_vector_type(4)));

// async global->LDS, 16B per lane. LDS dest must be lane-linear within the wave.
__device__ __forceinline__ void async16(const bf16* g, bf16* l) {
  __builtin_amdgcn_global_load_lds(
      (__attribute__((address_space(1))) void*)(void*)(const_cast<bf16*>(g)),
      (__attribute__((address_space(3))) void*)(void*)l,
      16, 0, 0);
}

// ---------------- elementwise converts / transposes / gathers ----------------

__global__ void cvt_bf16(const float* __restrict__ s, bf16* __restrict__ d, int n) {
  int i = blockIdx.x * blockDim.x + threadIdx.x;
  int stride = gridDim.x * blockDim.x;
  for (int k = i; k < n; k += stride) d[k] = (bf16)s[k];
}

// dst[c, r] = src[r, c]; src is R x C f32 (row-major), dst is C x R bf16.
__global__ void transpose_to_bf16(const float* __restrict__ src, bf16* __restrict__ dst,
                                  int R, int C) {
  __shared__ float tile[32][33];
  int c0 = blockIdx.x * 32, r0 = blockIdx.y * 32;
  int tx = threadIdx.x, ty = threadIdx.y;
#pragma unroll
  for (int k = 0; k < 32; k += 8)
    tile[ty + k][tx] = src[(size_t)(r0 + ty + k) * C + (c0 + tx)];
  __syncthreads();
#pragma unroll
  for (int k = 0; k < 32; k += 8)
    dst[(size_t)(c0 + ty + k) * R + (r0 + tx)] = (bf16)tile[tx][ty + k];
}

// X[r = t*64+b, :] = bf16(emb[tokens[b,t], :]), rows >= 3008 zeroed (M padded to 3072)
__global__ void gather_emb(const int* __restrict__ tokens, const float* __restrict__ emb,
                           bf16* __restrict__ X) {
  int r = blockIdx.x;
  int tid = threadIdx.x;
  if (r < 3008) {
    int t = r >> 6, b = r & 63;
    int tok = tokens[b * 47 + t];
    const float* e = emb + (size_t)tok * 512;
    for (int k = tid; k < 512; k += 128) X[(size_t)r * 512 + k] = (bf16)e[k];
  } else {
    for (int k = tid; k < 512; k += 128) X[(size_t)r * 512 + k] = (bf16)0.f;
  }
}

// S0[b, 0:1024] = bf16(enc_h), S0[b, 1024:2048] = 0; block 0 zeroes the sync flags.
__global__ void init_state(const float* __restrict__ enc_h, bf16* __restrict__ S0,
                           unsigned int* __restrict__ flags) {
  int i = blockIdx.x * 256 + threadIdx.x;   // 0..65535
  int b = i >> 10, u = i & 1023;
  S0[(size_t)b * 2048 + u]        = (bf16)enc_h[i];
  S0[(size_t)b * 2048 + 1024 + u] = (bf16)0.f;
  if (blockIdx.x == 0 && threadIdx.x < 128) flags[threadIdx.x] = 0u;
}

// ---------------- generic bt-GEMM: C[M,N] = A[M,K] @ B[N,K]^T ----------------
// m97 structure: 128x128 tile, BK=32, 4 waves (2x2), 64x64 per wave, 16x16x32 bf16 MFMA.
// MODE 0: bf16 C      MODE 1: bf16 C, += RT[r,c] for c<1024 (W12T build)
// MODE 2: f32 C, += aux[c] (bias)     MODE 3: logits scatter, += aux[c], mask r<3008
// MODE 4: plain f32 C
template <int MODE>
__global__ __launch_bounds__(256) void gemm_bt(
    const bf16* __restrict__ A, int lda,
    const bf16* __restrict__ B, int ldb, int K,
    void* __restrict__ C, int ldc,
    const void* __restrict__ aux) {
  __shared__ bf16 As[128 * 32];
  __shared__ bf16 Bs[128 * 32];
  const int tid = threadIdx.x;
  const int wave = tid >> 6, lane = tid & 63;
  const int wm = wave >> 1, wn = wave & 1;
  const int quad = lane >> 4, l16 = lane & 15;
  const size_t r0 = (size_t)blockIdx.y * 128;
  const size_t c0 = (size_t)blockIdx.x * 128;

  f32x4 acc[4][4] = {};

  for (int k0 = 0; k0 < K; k0 += 32) {
#pragma unroll
    for (int j = 0; j < 2; ++j) {
      int seg = j * 256 + tid;
      int row = seg >> 2, ks = seg & 3;
      async16(A + (r0 + row) * (size_t)lda + k0 + ks * 8, As + seg * 8);
    }
#pragma unroll
    for (int j = 0; j < 2; ++j) {
      int seg = j * 256 + tid;
      int row = seg >> 2, ks = seg & 3;
      async16(B + (c0 + row) * (size_t)ldb + k0 + ks * 8, Bs + seg * 8);
    }
    __syncthreads();
    bf16x8 af[4], bfr[4];
#pragma unroll
    for (int mi = 0; mi < 4; ++mi)
      af[mi] = *(const bf16x8*)(As + (wm * 64 + mi * 16 + l16) * 32 + quad * 8);
#pragma unroll
    for (int ni = 0; ni < 4; ++ni)
      bfr[ni] = *(const bf16x8*)(Bs + (wn * 64 + ni * 16 + l16) * 32 + quad * 8);
#pragma unroll
    for (int mi = 0; mi < 4; ++mi)
#pragma unroll
      for (int ni = 0; ni < 4; ++ni)
        acc[mi][ni] = __builtin_amdgcn_mfma_f32_16x16x32_bf16(af[mi], bfr[ni], acc[mi][ni], 0, 0, 0);
    __syncthreads();
  }

#pragma unroll
  for (int mi = 0; mi < 4; ++mi)
#pragma unroll
    for (int ni = 0; ni < 4; ++ni)
#pragma unroll
      for (int reg = 0; reg < 4; ++reg) {
        size_t r = r0 + wm * 64 + mi * 16 + quad * 4 + reg;
        size_t c = c0 + wn * 64 + ni * 16 + l16;
        float v = acc[mi][ni][reg];
        if (MODE == 0) {
          ((bf16*)C)[r * ldc + c] = (bf16)v;
        } else if (MODE == 1) {
          if (c < 1024) v += (float)((const bf16*)aux)[r * 1024 + c];
          ((bf16*)C)[r * ldc + c] = (bf16)v;
        } else if (MODE == 2) {
          v += ((const float*)aux)[c];
          ((float*)C)[r * ldc + c] = v;
        } else if (MODE == 3) {
          if (r < 3008) {
            size_t t = r >> 6, b = r & 63;
            ((float*)C)[(b * 47 + t) * (size_t)32000 + c] = v + ((const float*)aux)[c];
          }
        } else {
          ((float*)C)[r * ldc + c] = v;
        }
      }
}

// ---------------- fused decoder: all 47 steps in ONE regular launch ----------------
// 256 blocks x 256 threads (4 waves). Block p owns hidden cols [p*4, p*4+4) across the
// 4 gates -> 16 z-cols; its 16-row W12T panel (64 KB) is staged into LDS ONCE and reused
// for all 46 W12T steps. LSTM c state lives in one VGPR per thread. Cross-block sync via
// flag counters + __threadfence() (targeted wbl2/inv release/acquire), NOT grid.sync:
//   gates (all 256 blocks) -> flagA[t]==256 -> attention (blocks 0..63) -> flagB[t]==64.
// Deadlock-free without cooperative launch: LDS 68.3 KB => every CU can host 2 blocks,
// so 256 blocks are provably all co-resident.
// Math is bit-identical to the 2-kernel-per-step version (same MFMA order).
__global__ __launch_bounds__(256) void decoder_fused(
    const bf16* __restrict__ S0,       // [64,2048]  (h=enc_h, ctx=0)
    const bf16* __restrict__ W12T,     // [4096,2048]
    const bf16* __restrict__ RT,       // [4096,1024] (t=0 weights)
    const float* __restrict__ precomp, // [3072,4096]
    const float* __restrict__ enc_c,   // [64,1024]
    const float* __restrict__ keys,    // [4096,1024] f32
    const bf16* __restrict__ memB,     // [4096,1024]
    bf16* __restrict__ HC,             // [3072,2048]
    unsigned int* __restrict__ flags)  // [0..46]=gates done, [64..110]=attn done
{
  __shared__ bf16 Bs[16 * 2048];       // 64 KB weight panel (XOR-swizzled rows)
  __shared__ float zs[64 * 16];        // 4 KB gate pre-activations
  __shared__ float sm[64];             // attention scores/aligns

  const int tid = threadIdx.x;
  const int p = blockIdx.x;            // 0..255
  const int wave = tid >> 6, lane = tid & 63;
  const int quad = lane >> 4, l16 = lane & 15;
  const int growB = (l16 >> 2) * 1024 + p * 4 + (l16 & 3);  // this lane's global z-col

  // ---- stage W12T panel once: LDS[n][kb] = G[n][kb ^ ((n&7)<<4)] ----
#pragma unroll
  for (int i = 0; i < 16; ++i) {
    int seg = i * 256 + tid;
    int n = seg >> 8;                  // row 0..15 (uniform per iteration)
    int ko = seg & 255;
    int gkb = (ko * 16) ^ ((n & 7) << 4);
    int ng = (n >> 2) * 1024 + p * 4 + (n & 3);
    async16(W12T + (size_t)ng * 2048 + (gkb >> 1), Bs + n * 2048 + ko * 8);
  }

  // ---- c state in a register: thread covers (b = tid>>2, s = tid&3) ----
  float c_reg;
  {
    int b = tid >> 2, s = tid & 3;
    c_reg = enc_c[b * 1024 + p * 4 + s];
  }

  const char* bbase = (const char*)Bs + l16 * 4096;
  const int bswz = (l16 & 7) << 4;

  __syncthreads();                     // staging drain

  for (int t = 0; t < 47; ++t) {
    const bf16* Sin = t ? (HC + (size_t)(t - 1) * 131072) : S0;
    bf16* HC_t = HC + (size_t)t * 131072;
    const float* pct = precomp + (size_t)t * 262144;
    const bf16* arow = Sin + (size_t)(wave * 16 + l16) * 2048 + quad * 8;

    // ---- gates GEMM: z[64 rows, 16 local cols] ----
    f32x4 acc0 = {}, acc1 = {};
    if (t == 0) {
      const bf16* brow = RT + (size_t)growB * 1024 + quad * 8;
#pragma unroll 8
      for (int ks = 0; ks < 32; ks += 2) {
        bf16x8 b0 = *(const bf16x8*)(brow + ks * 32);
        bf16x8 a0 = *(const bf16x8*)(arow + (size_t)ks * 32);
        acc0 = __builtin_amdgcn_mfma_f32_16x16x32_bf16(a0, b0, acc0, 0, 0, 0);
        bf16x8 b1 = *(const bf16x8*)(brow + (ks + 1) * 32);
        bf16x8 a1 = *(const bf16x8*)(arow + (size_t)(ks + 1) * 32);
        acc1 = __builtin_amdgcn_mfma_f32_16x16x32_bf16(a1, b1, acc1, 0, 0, 0);
      }
    } else {
#pragma unroll 8
      for (int ks = 0; ks < 64; ks += 2) {
        bf16x8 b0 = *(const bf16x8*)(bbase + ((ks * 64 + quad * 16) ^ bswz));
        bf16x8 a0 = *(const bf16x8*)(arow + (size_t)ks * 32);
        acc0 = __builtin_amdgcn_mfma_f32_16x16x32_bf16(a0, b0, acc0, 0, 0, 0);
        bf16x8 b1 = *(const bf16x8*)(bbase + (((ks + 1) * 64 + quad * 16) ^ bswz));
        bf16x8 a1 = *(const bf16x8*)(arow + (size_t)(ks + 1) * 32);
        acc1 = __builtin_amdgcn_mfma_f32_16x16x32_bf16(a1, b1, acc1, 0, 0, 0);
      }
    }

    // ---- z + precomp -> zs[row][l16] ----
#pragma unroll
    for (int reg = 0; reg < 4; ++reg) {
      int row = wave * 16 + quad * 4 + reg;
      zs[row * 16 + l16] = acc0[reg] + acc1[reg] + pct[(size_t)row * 4096 + growB];
    }
    __syncthreads();

    // ---- LSTM pointwise; h2 -> HC_t, c stays in reg ----
    {
      int b = tid >> 2, s = tid & 3;
      float iv = zs[b * 16 + s];
      float fv = zs[b * 16 + 4 + s];
      float gv = zs[b * 16 + 8 + s];
      float ov = zs[b * 16 + 12 + s];
      float ig = 1.f / (1.f + __expf(-iv));
      float fg = 1.f / (1.f + __expf(-fv));
      float og = 1.f / (1.f + __expf(-ov));
      float c2 = fg * c_reg + ig * tanhf(gv);
      float h2 = og * tanhf(c2);
      c_reg = c2;
      HC_t[(size_t)b * 2048 + p * 4 + s] = (bf16)h2;
    }
    __syncthreads();                   // __syncthreads drains vmcnt(0): h2 stores in L2
    if (tid == 0) {
      __threadfence();                 // release: wbl2 -> h2 visible at LLC
      __hip_atomic_fetch_add(&flags[t], 1u, __ATOMIC_RELAXED, __HIP_MEMORY_SCOPE_AGENT);
    }

    // ---- Luong attention: blocks 0..63, one per batch ----
    if (p < 64) {
      if (tid == 0) {
        while (__hip_atomic_load(&flags[t], __ATOMIC_RELAXED, __HIP_MEMORY_SCOPE_AGENT) < 256u)
          __builtin_amdgcn_s_sleep(2);
        __threadfence();               // acquire: inv -> fresh h2
      }
      __syncthreads();

      const int b = p;
      float hv[16];
      {
        const bf16* hp = HC_t + (size_t)b * 2048 + lane * 16;
        bf16x8 h0 = *(const bf16x8*)(hp);
        bf16x8 h1 = *(const bf16x8*)(hp + 8);
#pragma unroll
        for (int e = 0; e < 8; ++e) { hv[e] = (float)h0[e]; hv[8 + e] = (float)h1[e]; }
      }

#pragma unroll 4
      for (int ii = 0; ii < 16; ++ii) {
        int it = wave * 16 + ii;
        const float* krow = keys + ((size_t)b * 64 + it) * 1024 + lane * 16;
        f32x4 k0 = *(const f32x4*)(krow);
        f32x4 k1 = *(const f32x4*)(krow + 4);
        f32x4 k2 = *(const f32x4*)(krow + 8);
        f32x4 k3 = *(const f32x4*)(krow + 12);
        float pr = hv[0] * k0[0] + hv[1] * k0[1] + hv[2] * k0[2] + hv[3] * k0[3]
                 + hv[4] * k1[0] + hv[5] * k1[1] + hv[6] * k1[2] + hv[7] * k1[3]
                 + hv[8] * k2[0] + hv[9] * k2[1] + hv[10] * k2[2] + hv[11] * k2[3]
                 + hv[12] * k3[0] + hv[13] * k3[1] + hv[14] * k3[2] + hv[15] * k3[3];
#pragma unroll
        for (int off = 32; off > 0; off >>= 1) pr += __shfl_xor(pr, off);
        if (lane == 0) sm[it] = pr;
      }
      __syncthreads();

      if (tid < 64) {
        float s = sm[tid];
        float mx = s;
#pragma unroll
        for (int off = 32; off > 0; off >>= 1) mx = fmaxf(mx, __shfl_xor(mx, off));
        float e = __expf(s - mx);
        float sum = e;
#pragma unroll
        for (int off = 32; off > 0; off >>= 1) sum += __shfl_xor(sum, off);
        sm[tid] = e / sum;
      }
      __syncthreads();

      int u0 = tid * 4;
      float a0 = 0.f, a1 = 0.f, a2 = 0.f, a3 = 0.f;
#pragma unroll 4
      for (int i = 0; i < 64; ++i) {
        float al = sm[i];
        bf16x4 m4 = *(const bf16x4*)(memB + ((size_t)b * 64 + i) * 1024 + u0);
        a0 += al * (float)m4[0];
        a1 += al * (float)m4[1];
        a2 += al * (float)m4[2];
        a3 += al * (float)m4[3];
      }
      bf16* so = HC_t + (size_t)b * 2048 + 1024 + u0;
      so[0] = (bf16)a0;
      so[1] = (bf16)a1;
      so[2] = (bf16)a2;
      so[3] = (bf16)a3;
      __syncthreads();                 // drain ctx stores
      if (tid == 0) {
        __threadfence();               // release ctx
        __hip_atomic_fetch_add(&flags[64 + t], 1u, __ATOMIC_RELAXED, __HIP_MEMORY_SCOPE_AGENT);
      }
    }

    // ---- everyone waits for ctx before reading Sin(t) next iteration ----
    if (t < 46) {
      if (tid == 0) {
        while (__hip_atomic_load(&flags[64 + t], __ATOMIC_RELAXED, __HIP_MEMORY_SCOPE_AGENT) < 64u)
          __builtin_amdgcn_s_sleep(2);
        __threadfence();               // acquire: fresh h2+ctx for next step
      }
      __syncthreads();
    }
  }
}

// ---------------- driver ----------------

extern "C" void kernel_launch(void* const* d_in, const int* in_sizes, int n_in,
                              void* d_out, int out_size, void* d_ws, size_t ws_size,
                              hipStream_t stream) {
  const int*   tokens = (const int*)d_in[0];
  const float* memory = (const float*)d_in[1];
  const float* enc_h  = (const float*)d_in[2];
  const float* enc_c  = (const float*)d_in[3];
  const float* emb    = (const float*)d_in[4];
  const float* Wm     = (const float*)d_in[5];
  const float* Wa     = (const float*)d_in[6];
  const float* lstm_k = (const float*)d_in[7];
  const float* lstm_r = (const float*)d_in[8];
  const float* lstm_b = (const float*)d_in[9];
  const float* fc_w   = (const float*)d_in[10];
  const float* fc_b   = (const float*)d_in[11];
  float* out = (float*)d_out;

  // scratch inside d_out (dead before the final logits GEMM writes out)
  char* ob = (char*)d_out;
  size_t off = 0;
  auto alloc_o = [&](size_t bytes) { char* q = ob + off; off += bytes; return q; };
  bf16*  memB    = (bf16*)alloc_o(8388608);        // [4096,1024] bf16
  float* keys    = (float*)alloc_o(16777216);      // [4096,1024] f32
  bf16*  WaB     = (bf16*)alloc_o(4194304);        // [2048,1024] bf16
  bf16*  WmT     = (bf16*)alloc_o(2097152);        // [1024,1024]
  bf16*  KpT     = (bf16*)alloc_o(8388608);        // [4096,1024]
  bf16*  KxT     = (bf16*)alloc_o(4194304);        // [4096,512]
  bf16*  RT      = (bf16*)alloc_o(8388608);        // [4096,1024]
  bf16*  WaT     = (bf16*)alloc_o(4194304);        // [1024,2048]
  bf16*  X       = (bf16*)alloc_o(3145728);        // [3072,512]
  bf16*  W12T    = (bf16*)alloc_o(16777216);       // [4096,2048]
  bf16*  S0      = (bf16*)alloc_o(262144);         // [64,2048]
  bf16*  HC      = (bf16*)alloc_o(12582912);       // [3072,2048]
  float* precomp = (float*)alloc_o(50331648);      // [3072,4096] f32
  unsigned int* flags = (unsigned int*)alloc_o(512); // [128] sync counters

  // d_ws: only what is live during the final logits GEMM
  char* wb = (char*)d_ws;
  bf16* fcwT  = (bf16*)(wb);                       // [32000,1024] bf16 (65,536,000 B)
  bf16* attnb = (bf16*)(wb + 65536000);            // [3072,1024] bf16

  dim3 tb(32, 8);

  // precompute / converts
  cvt_bf16<<<2048, 256, 0, stream>>>(memory, memB, 4194304);
  cvt_bf16<<<2048, 256, 0, stream>>>(Wa, WaB, 2097152);
  transpose_to_bf16<<<dim3(32, 32), tb, 0, stream>>>(Wm, WmT, 1024, 1024);
  transpose_to_bf16<<<dim3(128, 32), tb, 0, stream>>>(lstm_k + (size_t)512 * 4096, KpT, 1024, 4096);
  transpose_to_bf16<<<dim3(128, 16), tb, 0, stream>>>(lstm_k, KxT, 512, 4096);
  transpose_to_bf16<<<dim3(128, 32), tb, 0, stream>>>(lstm_r, RT, 1024, 4096);
  transpose_to_bf16<<<dim3(32, 64), tb, 0, stream>>>(Wa, WaT, 2048, 1024);
  transpose_to_bf16<<<dim3(1000, 32), tb, 0, stream>>>(fc_w, fcwT, 1024, 32000);
  gather_emb<<<3072, 128, 0, stream>>>(tokens, emb, X);
  init_state<<<256, 256, 0, stream>>>(enc_h, S0, flags);

  // keys = memory @ Wm  (f32 out)
  gemm_bt<4><<<dim3(8, 32), 256, 0, stream>>>(memB, 1024, WmT, 1024, 1024, keys, 1024, nullptr);
  // W12T[n, m] = (Wa@Kp)[m, n] + (m<1024 ? lstm_r[m, n] : 0)   (bf16 out)
  gemm_bt<1><<<dim3(16, 32), 256, 0, stream>>>(KpT, 1024, WaB, 1024, 1024, W12T, 2048, RT);
  // precomp = X @ lstm_k[0:512] + lstm_b   (f32 out)
  gemm_bt<2><<<dim3(32, 24), 256, 0, stream>>>(X, 512, KxT, 512, 512, precomp, 4096, lstm_b);

  // recurrence: ONE launch, 47 steps, flag-based cross-block sync
  decoder_fused<<<256, 256, 0, stream>>>(S0, W12T, RT, precomp, enc_c, keys, memB, HC, flags);

  // attn_all = HC @ Wa   (bf16 out)
  gemm_bt<0><<<dim3(8, 24), 256, 0, stream>>>(HC, 2048, WaT, 2048, 2048, attnb, 1024, nullptr);
  // logits = attn_all @ fc_w + fc_b, scattered to out[b, t, v]  (non-SWAP grid: measured faster)
  gemm_bt<3><<<dim3(250, 24), 256, 0, stream>>>(attnb, 1024, fcwT, 1024, 1024, out, 32000, fc_b);

  (void)in_sizes; (void)n_in; (void)out_size; (void)ws_size;
}